// Round 14
// baseline (136.568 us; speedup 1.0000x reference)
//
#include <hip/hip_runtime.h>
#include <math.h>

typedef unsigned int   u32;
typedef unsigned long long u64;

#define BATCH   8
#define NDATA   8192
#define NPOINT  1024
#define NSAMPLE 32
#define CFEAT   64
#define ROWF    67            // 3 xyz + 64 feat
#define MAXCAND 128           // P(#in-radius > 128) ~ 0
#define QPW     2             // queries per wave
#define QPB     8             // queries per block (4 waves)
#define TILE    512           // points per LDS tile
#define DWT     (TILE*3)      // 1536 dwords per tile
#define NT      (NDATA/TILE)  // 16 tiles
#define PLANE   516           // padded plane stride (dwords, 16B-aligned, banks shifted)

// f32-element offsets of the concatenated outputs
#define OUT_IDX (BATCH*NPOINT*NSAMPLE*ROWF)              // 17563648
#define OUT_GX  (OUT_IDX + BATCH*NPOINT*NSAMPLE)         // 17825792

// f32 -> bf16 (RNE) -> f32: match the harness's bf16-rounded np reference
__device__ __forceinline__ float rnbf(float f) {
    u32 b = __float_as_uint(f);
    b += 0x7FFFu + ((b >> 16) & 1u);
    return __uint_as_float(b & 0xFFFF0000u);
}
__device__ __forceinline__ int clampidx(int v) {
    return (v < 0) ? 0 : (v > NDATA-1 ? NDATA-1 : v);
}

__global__ __launch_bounds__(256, 4)   // 4 waves/EU -> 16 waves/CU, VGPR <= 128
void grouping_kernel(const float* __restrict__ new_xyz,
                     const float* __restrict__ xyz,
                     const float* __restrict__ points,
                     float* __restrict__ out, float T)
{
    __shared__ __align__(16) float S[2][3*PLANE];   // xs/ys/zs planes (2 x 6.2 KB)
    __shared__ float cand_s[QPB][MAXCAND];          // f32 sqrt(d2)
    __shared__ int   cand_i[QPB][MAXCAND];          // point index (tie-break key)
    __shared__ int   sel[QPB][NSAMPLE];

    const int tid  = threadIdx.x;
    const int wv   = tid >> 6;
    const int lane = tid & 63;
    const int q0   = blockIdx.x * QPB + wv * QPW;   // wave's first query
    const int b    = q0 >> 10;                      // batch (8 | 1024 -> uniform/block)

    sel[wv*QPW + (lane >> 5)][lane & 31] = 0;       // safety net; overwritten below

    float qx[QPW], qy[QPW], qz[QPW];
    #pragma unroll
    for (int j = 0; j < QPW; ++j) {
        qx[j] = new_xyz[(q0+j)*3 + 0];
        qy[j] = new_xyz[(q0+j)*3 + 1];
        qz[j] = new_xyz[(q0+j)*3 + 2];
    }
    const float* bx = xyz + (size_t)b * NDATA * 3;  // 96 KB/batch, L2-resident

    // ---- stage tile 0: coalesced global dwords -> SoA planes ----
    #pragma unroll
    for (int k = 0; k < DWT/256; ++k) {
        int w = k*256 + tid;                        // w = 3p + c
        int p = w / 3, c = w - 3*p;
        S[0][c*PLANE + p] = bx[w];
    }
    __syncthreads();

    // ---- scan: 3 x ds_read_b128 per 256 points, 2 queries per quad ----
    int n[QPW]; n[0] = 0; n[1] = 0;                 // wave-uniform counts
    for (int t = 0; t < NT; ++t) {
        const int cur = t & 1, nxt = cur ^ 1;
        if (t + 1 < NT) {                           // stage next tile
            #pragma unroll
            for (int k = 0; k < DWT/256; ++k) {
                int w = k*256 + tid;
                int p = w / 3, c = w - 3*p;
                S[nxt][c*PLANE + p] = bx[(t+1)*DWT + w];
            }
        }
        #pragma unroll
        for (int u = 0; u < TILE/256; ++u) {        // 2 quads per tile
            const float4 xv = ((const float4*)(S[cur]          ))[u*64 + lane];
            const float4 yv = ((const float4*)(S[cur] +   PLANE))[u*64 + lane];
            const float4 zv = ((const float4*)(S[cur] + 2*PLANE))[u*64 + lane];
            float d2v[QPW][4];
            u64   mv [QPW][4];
            u64 ored = 0;
            #pragma unroll
            for (int j = 0; j < 4; ++j) {
                float x = (&xv.x)[j], y = (&yv.x)[j], z = (&zv.x)[j];
                #pragma unroll
                for (int s = 0; s < QPW; ++s) {
                    // exact np f32 semantics: no FMA, left-to-right sum
                    float dx = __fsub_rn(x, qx[s]);
                    float dy = __fsub_rn(y, qy[s]);
                    float dz = __fsub_rn(z, qz[s]);
                    float d2 = __fadd_rn(__fadd_rn(__fmul_rn(dx,dx), __fmul_rn(dy,dy)),
                                         __fmul_rn(dz,dz));
                    d2v[s][j] = d2;
                    u64 m = __ballot(d2 < T);       // == sqrtf(d2) < 0.2f (monotone)
                    mv[s][j] = m;
                    ored |= m;
                }
            }
            if (ored) {                              // rare (~1/3 of iterations)
                #pragma unroll
                for (int s = 0; s < QPW; ++s) {
                    #pragma unroll
                    for (int j = 0; j < 4; ++j) {
                        u64 m = mv[s][j];
                        if (m) {
                            if (d2v[s][j] < T) {
                                int below = __builtin_amdgcn_mbcnt_hi((u32)(m >> 32),
                                             __builtin_amdgcn_mbcnt_lo((u32)m, 0));
                                int pos = n[s] + below;
                                if (pos < MAXCAND) {
                                    cand_s[wv*QPW + s][pos] = __fsqrt_rn(d2v[s][j]);
                                    cand_i[wv*QPW + s][pos] = t*TILE + u*256 + 4*lane + j;
                                }
                            }
                            n[s] += (int)__popcll(m);
                        }
                    }
                }
            }
        }
        __syncthreads();   // block-uniform: compute done + next tile staged
    }

    // ---- rare pass: argmin for empty-ball queries (exact np semantics) ----
    int mini[QPW]; mini[0] = 0; mini[1] = 0;
    #pragma unroll
    for (int s = 0; s < QPW; ++s) {
        if (n[s] == 0) {
            float mind = 3.402823466e38f; int mi = 0;
            for (int k = 0; k < NDATA/64; ++k) {
                int i = (k << 6) + lane;
                float dx = __fsub_rn(bx[i*3+0], qx[s]);
                float dy = __fsub_rn(bx[i*3+1], qy[s]);
                float dz = __fsub_rn(bx[i*3+2], qz[s]);
                float d2 = __fadd_rn(__fadd_rn(__fmul_rn(dx,dx), __fmul_rn(dy,dy)),
                                     __fmul_rn(dz,dz));
                if (d2 < mind) { mind = d2; mi = i; }
            }
            float ms = __fsqrt_rn(mind);            // np tie rule on sqrt values
            for (int off = 32; off; off >>= 1) {
                float os = __shfl_xor(ms, off);
                int   oi = __shfl_xor(mi, off);
                if (os < ms || (os == ms && oi < mi)) { ms = os; mi = oi; }
            }
            mini[s] = mi;
        }
    }

    __syncthreads();

    // ---- rank-place: (dist, point-index) lex == np stable argsort ----
    #pragma unroll
    for (int s = 0; s < QPW; ++s) {
        const int wq = wv*QPW + s;
        const int nj = n[s] > MAXCAND ? MAXCAND : n[s];
        for (int kk = lane; kk < nj; kk += 64) {
            float sk = cand_s[wq][kk];
            int   ik = cand_i[wq][kk];
            int r = 0;
            for (int mm = 0; mm < nj; ++mm) {        // broadcast LDS reads
                float sm = cand_s[wq][mm];
                int   im = cand_i[wq][mm];
                r += (int)((sm < sk) | ((sm == sk) & (im < ik)));
            }
            if (r < NSAMPLE) sel[wq][r] = clampidx(ik);
        }
    }
    __syncthreads();
    #pragma unroll
    for (int s = 0; s < QPW; ++s) {
        const int wq = wv*QPW + s;
        const int nj = n[s] > MAXCAND ? MAXCAND : n[s];
        const int nsel = nj < NSAMPLE ? nj : NSAMPLE;
        if (lane >= nsel && lane < NSAMPLE) {
            int pad = (nj > 0) ? sel[wq][0] : clampidx(mini[s]);   // sorted_idx[0]
            sel[wq][lane] = pad;
        }
    }
    __syncthreads();

    // ---- outputs: f32 stores, values pre-rounded through bf16 ----
    const float* prow = points + (size_t)b * NDATA * CFEAT;
    #pragma unroll
    for (int s = 0; s < QPW; ++s) {
        const int q  = q0 + s;
        const int wq = wv*QPW + s;

        // idx (chunk 1)
        if (lane < NSAMPLE)
            out[OUT_IDX + (size_t)q*NSAMPLE + lane] = rnbf((float)sel[wq][lane]);

        // grouped_xyz (chunk 2)
        for (int e = lane; e < NSAMPLE*3; e += 64) {
            int sR = e / 3, c2 = e - sR*3;
            int is = sel[wq][sR];
            out[OUT_GX + (size_t)q*(NSAMPLE*3) + e] = rnbf(bx[is*3 + c2]);
        }

        // new_points (chunk 0): row-major pass -> each 64 B line written once
        float* onp = out + (size_t)q * (NSAMPLE*ROWF);
        for (int e = lane; e < NSAMPLE*ROWF; e += 64) {
            int sR = e / ROWF;
            int c2 = e - sR*ROWF;
            int is = sel[wq][sR];
            const float* ap = (c2 < 3) ? (bx + (size_t)is*3 + c2)
                                       : (prow + (size_t)is*CFEAT + (c2-3));
            onp[e] = rnbf(*ap);
        }
    }
}

extern "C" void kernel_launch(void* const* d_in, const int* in_sizes, int n_in,
                              void* d_out, int out_size, void* d_ws, size_t ws_size,
                              hipStream_t stream) {
    // T = smallest f32 x with sqrtf(x) >= 0.2f  =>  (d2 < T) == (sqrtf(d2) < 0.2f)
    union { u32 u; float f; } lo, hi, mid;
    lo.u = 0u; hi.f = 0.05f;
    while (hi.u - lo.u > 1u) {
        mid.u = lo.u + (hi.u - lo.u) / 2u;
        if (sqrtf(mid.f) >= 0.2f) hi.u = mid.u; else lo.u = mid.u;
    }
    float T = hi.f;

    grouping_kernel<<<(BATCH*NPOINT)/QPB, 256, 0, stream>>>(
        (const float*)d_in[0],   // new_xyz (f32)
        (const float*)d_in[1],   // xyz     (f32)
        (const float*)d_in[2],   // points  (f32)
        (float*)d_out, T);
}

// Round 15
// 131.575 us; speedup vs baseline: 1.0380x; 1.0380x over previous
//
#include <hip/hip_runtime.h>
#include <math.h>

typedef unsigned int   u32;
typedef unsigned long long u64;

#define BATCH   8
#define NDATA   8192
#define NPOINT  1024
#define NSAMPLE 32
#define CFEAT   64
#define ROWF    67            // 3 xyz + 64 feat
#define MAXCAND 128           // P(#in-radius > 128) ~ 0
#define QPB     4             // queries per block = waves per block (QPW=1)
#define TILE    512           // points per LDS tile
#define DWT     (TILE*3)      // 1536 dwords per tile
#define NT      (NDATA/TILE)  // 16 tiles
#define PLANE   516           // padded plane stride (dwords; %4==0 so 16B-aligned)

// f32-element offsets of the concatenated outputs
#define OUT_IDX (BATCH*NPOINT*NSAMPLE*ROWF)              // 17563648
#define OUT_GX  (OUT_IDX + BATCH*NPOINT*NSAMPLE)         // 17825792

// f32 -> bf16 (RNE) -> f32: match the harness's bf16-rounded np reference
__device__ __forceinline__ float rnbf(float f) {
    u32 b = __float_as_uint(f);
    b += 0x7FFFu + ((b >> 16) & 1u);
    return __uint_as_float(b & 0xFFFF0000u);
}
__device__ __forceinline__ int clampidx(int v) {
    return (v < 0) ? 0 : (v > NDATA-1 ? NDATA-1 : v);
}

__global__ __launch_bounds__(256, 8)   // 8 waves/EU -> 32 waves/CU, VGPR <= 64
void grouping_kernel(const float* __restrict__ new_xyz,
                     const float* __restrict__ xyz,
                     const float* __restrict__ points,
                     float* __restrict__ out, float T)
{
    __shared__ __align__(16) float S[2][3*PLANE];   // xs/ys/zs planes (2 x 6.2 KB)
    __shared__ float cand_s[QPB][MAXCAND];          // f32 sqrt(d2)
    __shared__ int   cand_i[QPB][MAXCAND];          // point index (tie-break key)
    __shared__ int   sel[QPB][NSAMPLE];

    const int tid  = threadIdx.x;
    const int wv   = tid >> 6;
    const int lane = tid & 63;
    const int q    = blockIdx.x * QPB + wv;   // one query per wave, < 8192
    const int b    = q >> 10;                 // batch (4 | 1024 -> uniform per block)

    if (lane < NSAMPLE) sel[wv][lane] = 0;    // safety net; overwritten below

    const float qx = new_xyz[q*3 + 0];
    const float qy = new_xyz[q*3 + 1];
    const float qz = new_xyz[q*3 + 2];
    const float* bx = xyz + (size_t)b * NDATA * 3;  // 96 KB/batch, L2-resident

    // ---- stage tile 0: coalesced global dwords -> SoA planes ----
    #pragma unroll
    for (int k = 0; k < DWT/256; ++k) {
        int w = k*256 + tid;                  // w = 3p + c
        int p = w / 3, c = w - 3*p;
        S[0][c*PLANE + p] = bx[w];
    }
    __syncthreads();

    // ---- scan: 3 x ds_read_b128 per 256 points, one query per wave ----
    int n = 0;                                // wave-uniform candidate count
    for (int t = 0; t < NT; ++t) {
        const int cur = t & 1, nxt = cur ^ 1;
        if (t + 1 < NT) {                     // stage next tile (coalesced reads)
            #pragma unroll
            for (int k = 0; k < DWT/256; ++k) {
                int w = k*256 + tid;
                int p = w / 3, c = w - 3*p;
                S[nxt][c*PLANE + p] = bx[(t+1)*DWT + w];
            }
        }
        #pragma unroll
        for (int u = 0; u < TILE/256; ++u) {  // 2 quads of 4 points/lane per tile
            const float4 xv = ((const float4*)(S[cur]          ))[u*64 + lane];
            const float4 yv = ((const float4*)(S[cur] +   PLANE))[u*64 + lane];
            const float4 zv = ((const float4*)(S[cur] + 2*PLANE))[u*64 + lane];
            #pragma unroll
            for (int j = 0; j < 4; ++j) {
                // exact np f32 semantics: no FMA, left-to-right sum
                float dx = __fsub_rn((&xv.x)[j], qx);
                float dy = __fsub_rn((&yv.x)[j], qy);
                float dz = __fsub_rn((&zv.x)[j], qz);
                float d2 = __fadd_rn(__fadd_rn(__fmul_rn(dx,dx), __fmul_rn(dy,dy)),
                                     __fmul_rn(dz,dz));
                bool cc = d2 < T;             // == sqrtf(d2) < 0.2f (monotone)
                u64 m = __ballot(cc);
                if (m) {                      // rare (~3% of point-ballots)
                    if (cc) {
                        int below = __builtin_amdgcn_mbcnt_hi((u32)(m >> 32),
                                     __builtin_amdgcn_mbcnt_lo((u32)m, 0));
                        int pos = n + below;
                        if (pos < MAXCAND) {
                            cand_s[wv][pos] = __fsqrt_rn(d2);   // ref sorts f32 norm
                            cand_i[wv][pos] = t*TILE + u*256 + 4*lane + j;
                        }
                    }
                    n += (int)__popcll(m);
                }
            }
        }
        __syncthreads();   // block-uniform: compute done + next tile staged
    }

    // ---- rare pass: argmin for empty-ball queries (exact np semantics) ----
    int mini = 0;
    if (n == 0) {
        float mind = 3.402823466e38f; int mi = 0;
        for (int k = 0; k < NDATA/64; ++k) {
            int i = (k << 6) + lane;
            float dx = __fsub_rn(bx[i*3+0], qx);
            float dy = __fsub_rn(bx[i*3+1], qy);
            float dz = __fsub_rn(bx[i*3+2], qz);
            float d2 = __fadd_rn(__fadd_rn(__fmul_rn(dx,dx), __fmul_rn(dy,dy)),
                                 __fmul_rn(dz,dz));
            if (d2 < mind) { mind = d2; mi = i; }   // strict <: lowest idx per lane
        }
        float ms = __fsqrt_rn(mind);                // np tie rule on sqrt values
        for (int off = 32; off; off >>= 1) {
            float os = __shfl_xor(ms, off);
            int   oi = __shfl_xor(mi, off);
            if (os < ms || (os == ms && oi < mi)) { ms = os; mi = oi; }
        }
        mini = mi;
    }

    __syncthreads();

    // ---- rank-place: (dist, point-index) lex == np stable argsort ----
    const int nj = n > MAXCAND ? MAXCAND : n;
    for (int kk = lane; kk < nj; kk += 64) {
        float sk = cand_s[wv][kk];
        int   ik = cand_i[wv][kk];
        int r = 0;
        for (int mm = 0; mm < nj; ++mm) {           // broadcast LDS reads
            float sm = cand_s[wv][mm];
            int   im = cand_i[wv][mm];
            r += (int)((sm < sk) | ((sm == sk) & (im < ik)));
        }
        if (r < NSAMPLE) sel[wv][r] = clampidx(ik);
    }
    __syncthreads();
    {
        const int nsel = nj < NSAMPLE ? nj : NSAMPLE;
        if (lane >= nsel && lane < NSAMPLE) {
            int pad = (nj > 0) ? sel[wv][0] : clampidx(mini);   // sorted_idx[0]
            sel[wv][lane] = pad;
        }
    }
    __syncthreads();

    // ---- outputs: f32 stores, values pre-rounded through bf16 ----
    // idx (chunk 1)
    if (lane < NSAMPLE)
        out[OUT_IDX + (size_t)q*NSAMPLE + lane] = rnbf((float)sel[wv][lane]);

    // grouped_xyz (chunk 2)
    for (int e = lane; e < NSAMPLE*3; e += 64) {
        int sR = e / 3, c2 = e - sR*3;
        int is = sel[wv][sR];
        out[OUT_GX + (size_t)q*(NSAMPLE*3) + e] = rnbf(bx[is*3 + c2]);
    }

    // new_points (chunk 0): row-major pass -> each 64 B line written once
    const float* prow = points + (size_t)b * NDATA * CFEAT;
    float* onp = out + (size_t)q * (NSAMPLE*ROWF);
    for (int e = lane; e < NSAMPLE*ROWF; e += 64) {
        int sR = e / ROWF;
        int c2 = e - sR*ROWF;
        int is = sel[wv][sR];
        const float* ap = (c2 < 3) ? (bx + (size_t)is*3 + c2)
                                   : (prow + (size_t)is*CFEAT + (c2-3));
        onp[e] = rnbf(*ap);
    }
}

extern "C" void kernel_launch(void* const* d_in, const int* in_sizes, int n_in,
                              void* d_out, int out_size, void* d_ws, size_t ws_size,
                              hipStream_t stream) {
    // T = smallest f32 x with sqrtf(x) >= 0.2f  =>  (d2 < T) == (sqrtf(d2) < 0.2f)
    union { u32 u; float f; } lo, hi, mid;
    lo.u = 0u; hi.f = 0.05f;
    while (hi.u - lo.u > 1u) {
        mid.u = lo.u + (hi.u - lo.u) / 2u;
        if (sqrtf(mid.f) >= 0.2f) hi.u = mid.u; else lo.u = mid.u;
    }
    float T = hi.f;

    grouping_kernel<<<(BATCH*NPOINT)/QPB, 256, 0, stream>>>(
        (const float*)d_in[0],   // new_xyz (f32)
        (const float*)d_in[1],   // xyz     (f32)
        (const float*)d_in[2],   // points  (f32)
        (float*)d_out, T);
}